// Round 6
// baseline (127.202 us; speedup 1.0000x reference)
//
#include <hip/hip_runtime.h>
#include <math.h>

// Attention_57406532878693: T=2048,B=32,D=1024,H=8,N=128,N2=16
#define T_   2048
#define B_   32
#define D_   1024
#define H_   8
#define N_   128
#define NK   16          // N2 gate width
#define BD4  (B_*D_/4)
#define PST  18          // P row stride in floats (bank-spread, float2-aligned)
#define LOG2E 1.4426950408889634f

typedef __attribute__((ext_vector_type(8))) short short8;   // bf16x8 frag
typedef __attribute__((ext_vector_type(4))) float f32x4;    // C/D frag

// split 8 fp32 (two float4) into truncated bf16 hi + bf16(lo) fragments
__device__ __forceinline__ void split_bf16(float4 a, float4 b,
                                           short8& hi, short8& lo) {
    union { uint32_t u[4]; short8 v; } H, L;
    uint32_t x0 = __float_as_uint(a.x), x1 = __float_as_uint(a.y);
    uint32_t x2 = __float_as_uint(a.z), x3 = __float_as_uint(a.w);
    uint32_t x4 = __float_as_uint(b.x), x5 = __float_as_uint(b.y);
    uint32_t x6 = __float_as_uint(b.z), x7 = __float_as_uint(b.w);
    H.u[0] = (x0 >> 16) | (x1 & 0xFFFF0000u);
    H.u[1] = (x2 >> 16) | (x3 & 0xFFFF0000u);
    H.u[2] = (x4 >> 16) | (x5 & 0xFFFF0000u);
    H.u[3] = (x6 >> 16) | (x7 & 0xFFFF0000u);
    float l0 = a.x - __uint_as_float(x0 & 0xFFFF0000u);
    float l1 = a.y - __uint_as_float(x1 & 0xFFFF0000u);
    float l2 = a.z - __uint_as_float(x2 & 0xFFFF0000u);
    float l3 = a.w - __uint_as_float(x3 & 0xFFFF0000u);
    float l4 = b.x - __uint_as_float(x4 & 0xFFFF0000u);
    float l5 = b.y - __uint_as_float(x5 & 0xFFFF0000u);
    float l6 = b.z - __uint_as_float(x6 & 0xFFFF0000u);
    float l7 = b.w - __uint_as_float(x7 & 0xFFFF0000u);
    L.u[0] = (__float_as_uint(l0) >> 16) | (__float_as_uint(l1) & 0xFFFF0000u);
    L.u[1] = (__float_as_uint(l2) >> 16) | (__float_as_uint(l3) & 0xFFFF0000u);
    L.u[2] = (__float_as_uint(l4) >> 16) | (__float_as_uint(l5) & 0xFFFF0000u);
    L.u[3] = (__float_as_uint(l6) >> 16) | (__float_as_uint(l7) & 0xFFFF0000u);
    hi = H.v; lo = L.v;
}

__device__ __forceinline__ float tanh_fast(float d) {
    return 1.f - 2.f * __frcp_rn(exp2f(d * (2.f * LOG2E)) + 1.f);
}

// load 8 float4 of x for one 16-t wave step (lane row t = s*128 + w*16 + kk)
#define LOADX(dst, s_) { \
    const int trow_ = (s_) * 128 + w * 16 + kk; \
    const size_t rb_ = (size_t)trow_ * BD4 + base4; \
    (dst)[0] = hyp4[rb_ + g * 2];      (dst)[1] = hyp4[rb_ + g * 2 + 1]; \
    (dst)[2] = hyp4[rb_ + 8 + g * 2];  (dst)[3] = hyp4[rb_ + 8 + g * 2 + 1]; \
    (dst)[4] = hyp4[rb_ + 16 + g * 2]; (dst)[5] = hyp4[rb_ + 16 + g * 2 + 1]; \
    (dst)[6] = hyp4[rb_ + 24 + g * 2]; (dst)[7] = hyp4[rb_ + 24 + g * 2 + 1]; }

// One block (512 thr, 8 waves) per (b,h). Pass 1: read x once -> colsums +
// P[t][k]=tanh(x.Ww+b) into LDS. Block-local mean -> gm. Pass 2: re-read x
// (L3-resident working set), logit from LDS P row, unshifted exp (|l|<=4),
// weighted accumulate. Direct out write. No workspace, no extra kernels.
__global__ __launch_bounds__(512, 2) void k_fused(
        const float* __restrict__ hyp,  const float* __restrict__ Ww,
        const float* __restrict__ Wb,   const float* __restrict__ Wmw,
        const float* __restrict__ Wmb,  const float* __restrict__ Whw,
        float* __restrict__ out) {
    __shared__ float Pl[T_ * PST];       // 147456 B
    __shared__ float red[8 * N_];        //   4096 B
    __shared__ float m_l[N_];
    __shared__ float gw_l[NK];
    __shared__ float zred[8];

    const int tid  = threadIdx.x;
    const int lane = tid & 63;
    const int w    = tid >> 6;           // wave 0..7
    const int bh   = blockIdx.x;
    const int b = bh >> 3, h = bh & 7;
    const float4* hyp4 = (const float4*)hyp;
    const float4* Ww4  = (const float4*)Ww;
    const int base4 = b * (D_ / 4) + h * (N_ / 4);
    const int kk = lane & 15;            // A-row / gate-k
    const int g  = lane >> 4;            // column group

    // W fragments (hi/lo bf16) + bias
    short8 wh[4], wlo[4];
#pragma unroll
    for (int ks = 0; ks < 4; ++ks) {
        float4 wa  = Ww4[kk * 32 + ks * 8 + g * 2];
        float4 wb4 = Ww4[kk * 32 + ks * 8 + g * 2 + 1];
        split_bf16(wa, wb4, wh[ks], wlo[ks]);
    }
    const float wbr = Wb[kk];

    // ---------------- PASS 1: colsums + P -> LDS ----------------
    float4 cs[8];
#pragma unroll
    for (int m = 0; m < 8; ++m) cs[m] = make_float4(0.f, 0.f, 0.f, 0.f);
    float4 xq[2][8];
    LOADX(xq[0], 0);
#pragma unroll
    for (int s = 0; s < 16; ++s) {
        const int cur = s & 1, nxt = cur ^ 1;
        if (s < 15) LOADX(xq[nxt], s + 1);
#pragma unroll
        for (int m = 0; m < 8; ++m) {
            cs[m].x += xq[cur][m].x; cs[m].y += xq[cur][m].y;
            cs[m].z += xq[cur][m].z; cs[m].w += xq[cur][m].w;
        }
        f32x4 acc = {0.f, 0.f, 0.f, 0.f};
#pragma unroll
        for (int ks = 0; ks < 4; ++ks) {
            short8 xh, xl;
            split_bf16(xq[cur][2*ks], xq[cur][2*ks+1], xh, xl);
            acc = __builtin_amdgcn_mfma_f32_16x16x32_bf16(xh, wh[ks],  acc, 0, 0, 0);
            acc = __builtin_amdgcn_mfma_f32_16x16x32_bf16(xl, wh[ks],  acc, 0, 0, 0);
            acc = __builtin_amdgcn_mfma_f32_16x16x32_bf16(xh, wlo[ks], acc, 0, 0, 0);
        }
        const int tl = s * 128 + w * 16 + g * 4;   // C row -> t = tl + i
#pragma unroll
        for (int i = 0; i < 4; ++i)
            Pl[(tl + i) * PST + kk] = tanh_fast(acc[i] + wbr);
    }
    // reduce colsums over kk (lane bits 0-3)
#pragma unroll
    for (int m = 0; m < 8; ++m) {
#pragma unroll
        for (int mask = 1; mask <= 8; mask <<= 1) {
            cs[m].x += __shfl_xor(cs[m].x, mask, 64);
            cs[m].y += __shfl_xor(cs[m].y, mask, 64);
            cs[m].z += __shfl_xor(cs[m].z, mask, 64);
            cs[m].w += __shfl_xor(cs[m].w, mask, 64);
        }
    }
    if (kk == 0) {
#pragma unroll
        for (int m = 0; m < 8; ++m) {
            int nb = 32 * (m >> 1) + 8 * g + 4 * (m & 1);
            red[w * N_ + nb + 0] = cs[m].x;
            red[w * N_ + nb + 1] = cs[m].y;
            red[w * N_ + nb + 2] = cs[m].z;
            red[w * N_ + nb + 3] = cs[m].w;
        }
    }
    __syncthreads();
    // ---------------- mean + gm (block-local) ----------------
    if (tid < N_) {
        float s = 0.f;
#pragma unroll
        for (int w8 = 0; w8 < 8; ++w8) s += red[w8 * N_ + tid];
        m_l[tid] = s * (1.f / (float)T_);
    }
    __syncthreads();
    if (tid < N_) {
        int k = tid >> 3, g3 = tid & 7;
        float dsum = 0.f;
#pragma unroll
        for (int i = 0; i < 16; ++i) {
            int n = g3 * 16 + i;
            dsum = fmaf(m_l[n], Wmw[k * N_ + n], dsum);
        }
        dsum += __shfl_xor(dsum, 1, 64);
        dsum += __shfl_xor(dsum, 2, 64);
        dsum += __shfl_xor(dsum, 4, 64);
        if (g3 == 0) gw_l[k] = tanhf(dsum + Wmb[k]) * Whw[k];
    }
    __syncthreads();
    float gmv[NK];
#pragma unroll
    for (int j = 0; j < NK; ++j) gmv[j] = gw_l[j];

    // ---------------- PASS 2: exp + weighted sum ----------------
    float4 cacc[8];
#pragma unroll
    for (int m = 0; m < 8; ++m) cacc[m] = make_float4(0.f, 0.f, 0.f, 0.f);
    float zacc = 0.f;
    LOADX(xq[0], 0);
#pragma unroll
    for (int s = 0; s < 16; ++s) {
        const int cur = s & 1, nxt = cur ^ 1;
        if (s < 15) LOADX(xq[nxt], s + 1);
        const int tr = s * 128 + w * 16 + kk;
        const float2* prow = (const float2*)&Pl[tr * PST];
        float lg = 0.f;
#pragma unroll
        for (int q = 0; q < 8; ++q) {
            float2 pv = prow[q];
            lg = fmaf(pv.x, gmv[2*q + 0], lg);
            lg = fmaf(pv.y, gmv[2*q + 1], lg);
        }
        float e = exp2f(lg * LOG2E);     // unshifted: |lg| <= sum|Whw| <= 4
        zacc += e;
#pragma unroll
        for (int m = 0; m < 8; ++m) {
            cacc[m].x = fmaf(e, xq[cur][m].x, cacc[m].x);
            cacc[m].y = fmaf(e, xq[cur][m].y, cacc[m].y);
            cacc[m].z = fmaf(e, xq[cur][m].z, cacc[m].z);
            cacc[m].w = fmaf(e, xq[cur][m].w, cacc[m].w);
        }
    }
    // reduce cacc + z over kk (lane bits 0-3)
#pragma unroll
    for (int m = 0; m < 8; ++m) {
#pragma unroll
        for (int mask = 1; mask <= 8; mask <<= 1) {
            cacc[m].x += __shfl_xor(cacc[m].x, mask, 64);
            cacc[m].y += __shfl_xor(cacc[m].y, mask, 64);
            cacc[m].z += __shfl_xor(cacc[m].z, mask, 64);
            cacc[m].w += __shfl_xor(cacc[m].w, mask, 64);
        }
    }
    float z = zacc;
    z += __shfl_xor(z, 1, 64);
    z += __shfl_xor(z, 2, 64);
    z += __shfl_xor(z, 4, 64);
    z += __shfl_xor(z, 8, 64);
    if (kk == 0) {
#pragma unroll
        for (int m = 0; m < 8; ++m) {
            int nb = 32 * (m >> 1) + 8 * g + 4 * (m & 1);
            red[w * N_ + nb + 0] = cacc[m].x;
            red[w * N_ + nb + 1] = cacc[m].y;
            red[w * N_ + nb + 2] = cacc[m].z;
            red[w * N_ + nb + 3] = cacc[m].w;
        }
    }
    if (lane == 0) zred[w] = z;
    __syncthreads();
    if (tid < N_) {
        float Z = ((zred[0] + zred[1]) + (zred[2] + zred[3]))
                + ((zred[4] + zred[5]) + (zred[6] + zred[7]));
        float c = 0.f;
#pragma unroll
        for (int w8 = 0; w8 < 8; ++w8) c += red[w8 * N_ + tid];
        out[bh * N_ + tid] = c / Z;
    }
}

extern "C" void kernel_launch(void* const* d_in, const int* in_sizes, int n_in,
                              void* d_out, int out_size, void* d_ws, size_t ws_size,
                              hipStream_t stream) {
    const float* hyp = (const float*)d_in[0];
    const float* Ww  = (const float*)d_in[1];
    const float* Wb  = (const float*)d_in[2];
    const float* Wmw = (const float*)d_in[3];
    const float* Wmb = (const float*)d_in[4];
    const float* Whw = (const float*)d_in[5];
    // d_in[6] = Wh_b: unused (softmax shift-invariant)
    float* out = (float*)d_out;

    k_fused<<<dim3(B_ * H_), 512, 0, stream>>>(hyp, Ww, Wb, Wmw, Wmb, Whw, out);
}

// Round 7
// 106.083 us; speedup vs baseline: 1.1991x; 1.1991x over previous
//
#include <hip/hip_runtime.h>
#include <hip/hip_fp16.h>
#include <math.h>

// Attention_57406532878693: T=2048,B=32,D=1024,H=8,N=128,N2=16
#define T_   2048
#define B_   32
#define D_   1024
#define H_   8
#define N_   128
#define NK   16          // N2 gate width
#define TSPL 8           // T-splits per (b,h)
#define TBLK (T_/TSPL)   // 256 t per block
#define BD4  (B_*D_/4)
#define APS  132         // attp stride per unit (128 c + Z + pad)
#define LOG2E 1.4426950408889634f

typedef __attribute__((ext_vector_type(8))) short short8;   // bf16x8 frag
typedef __attribute__((ext_vector_type(4))) float f32x4;    // C/D frag

// split 8 fp32 (two float4) into truncated bf16 hi + bf16(lo) fragments
__device__ __forceinline__ void split_bf16(float4 a, float4 b,
                                           short8& hi, short8& lo) {
    union { uint32_t u[4]; short8 v; } H, L;
    uint32_t x0 = __float_as_uint(a.x), x1 = __float_as_uint(a.y);
    uint32_t x2 = __float_as_uint(a.z), x3 = __float_as_uint(a.w);
    uint32_t x4 = __float_as_uint(b.x), x5 = __float_as_uint(b.y);
    uint32_t x6 = __float_as_uint(b.z), x7 = __float_as_uint(b.w);
    H.u[0] = (x0 >> 16) | (x1 & 0xFFFF0000u);
    H.u[1] = (x2 >> 16) | (x3 & 0xFFFF0000u);
    H.u[2] = (x4 >> 16) | (x5 & 0xFFFF0000u);
    H.u[3] = (x6 >> 16) | (x7 & 0xFFFF0000u);
    float l0 = a.x - __uint_as_float(x0 & 0xFFFF0000u);
    float l1 = a.y - __uint_as_float(x1 & 0xFFFF0000u);
    float l2 = a.z - __uint_as_float(x2 & 0xFFFF0000u);
    float l3 = a.w - __uint_as_float(x3 & 0xFFFF0000u);
    float l4 = b.x - __uint_as_float(x4 & 0xFFFF0000u);
    float l5 = b.y - __uint_as_float(x5 & 0xFFFF0000u);
    float l6 = b.z - __uint_as_float(x6 & 0xFFFF0000u);
    float l7 = b.w - __uint_as_float(x7 & 0xFFFF0000u);
    L.u[0] = (__float_as_uint(l0) >> 16) | (__float_as_uint(l1) & 0xFFFF0000u);
    L.u[1] = (__float_as_uint(l2) >> 16) | (__float_as_uint(l3) & 0xFFFF0000u);
    L.u[2] = (__float_as_uint(l4) >> 16) | (__float_as_uint(l5) & 0xFFFF0000u);
    L.u[3] = (__float_as_uint(l6) >> 16) | (__float_as_uint(l7) & 0xFFFF0000u);
    hi = H.v; lo = L.v;
}

__device__ __forceinline__ float tanh_fast(float d) {
    return 1.f - 2.f * __frcp_rn(exp2f(d * (2.f * LOG2E)) + 1.f);
}

// load 8 float4 of x for one 16-t step (lane's t-row = t0+step*64+w*16+kk)
#define LOADX(dst, step_) { \
    const int trow_ = t0 + (step_) * 64 + w * 16 + kk; \
    const size_t rb_ = (size_t)trow_ * BD4 + base4; \
    (dst)[0] = hyp4[rb_ + g * 2];      (dst)[1] = hyp4[rb_ + g * 2 + 1]; \
    (dst)[2] = hyp4[rb_ + 8 + g * 2];  (dst)[3] = hyp4[rb_ + 8 + g * 2 + 1]; \
    (dst)[4] = hyp4[rb_ + 16 + g * 2]; (dst)[5] = hyp4[rb_ + 16 + g * 2 + 1]; \
    (dst)[6] = hyp4[rb_ + 24 + g * 2]; (dst)[7] = hyp4[rb_ + 24 + g * 2 + 1]; }

// K1: one block per (bh,spl). One x read: colsums -> part[blk][128],
// P[t][k] = tanh(x.Ww + b) -> Pbuf (fp16). Single-buffered loads; latency
// hidden by 4 blocks/CU (launch_bounds(256,4) -> VGPR<=128, 16 waves/CU).
__global__ __launch_bounds__(256, 4) void k_p(const float* __restrict__ hyp,
                                              const float* __restrict__ Ww,
                                              const float* __restrict__ Wb,
                                              float* __restrict__ part,
                                              __half* __restrict__ Pbuf) {
    __shared__ float red[4 * N_];
    const int tid  = threadIdx.x;
    const int lane = tid & 63;
    const int w    = tid >> 6;
    const int blk  = blockIdx.x;
    const int bh   = blk >> 3;
    const int spl  = blk & 7;
    const int b = bh >> 3, h = bh & 7;
    const int t0 = spl * TBLK;
    const float4* hyp4 = (const float4*)hyp;
    const float4* Ww4  = (const float4*)Ww;
    const int base4 = b * (D_ / 4) + h * (N_ / 4);
    const int kk = lane & 15;
    const int g  = lane >> 4;

    short8 wh[4], wlo[4];
#pragma unroll
    for (int ks = 0; ks < 4; ++ks) {
        float4 wa  = Ww4[kk * 32 + ks * 8 + g * 2];
        float4 wb4 = Ww4[kk * 32 + ks * 8 + g * 2 + 1];
        split_bf16(wa, wb4, wh[ks], wlo[ks]);
    }
    const float wbr = Wb[kk];

    float4 cs[8];
#pragma unroll
    for (int m = 0; m < 8; ++m) cs[m] = make_float4(0.f, 0.f, 0.f, 0.f);

#pragma unroll
    for (int step = 0; step < 4; ++step) {
        float4 xq[8];
        LOADX(xq, step);
#pragma unroll
        for (int m = 0; m < 8; ++m) {
            cs[m].x += xq[m].x; cs[m].y += xq[m].y;
            cs[m].z += xq[m].z; cs[m].w += xq[m].w;
        }
        f32x4 acc = {0.f, 0.f, 0.f, 0.f};
#pragma unroll
        for (int ks = 0; ks < 4; ++ks) {
            short8 xh, xl;
            split_bf16(xq[2*ks], xq[2*ks+1], xh, xl);
            acc = __builtin_amdgcn_mfma_f32_16x16x32_bf16(xh, wh[ks],  acc, 0, 0, 0);
            acc = __builtin_amdgcn_mfma_f32_16x16x32_bf16(xl, wh[ks],  acc, 0, 0, 0);
            acc = __builtin_amdgcn_mfma_f32_16x16x32_bf16(xh, wlo[ks], acc, 0, 0, 0);
        }
        // P[t = t0+step*64+w*16+g*4+i][kk] as fp16
        const int tl = t0 + step * 64 + w * 16 + g * 4;
        const size_t pb = ((size_t)bh * T_ + tl) * NK + kk;
#pragma unroll
        for (int i = 0; i < 4; ++i)
            Pbuf[pb + (size_t)i * NK] = __float2half(tanh_fast(acc[i] + wbr));
    }
    // reduce colsums over kk (lane bits 0-3)
#pragma unroll
    for (int m = 0; m < 8; ++m) {
#pragma unroll
        for (int mask = 1; mask <= 8; mask <<= 1) {
            cs[m].x += __shfl_xor(cs[m].x, mask, 64);
            cs[m].y += __shfl_xor(cs[m].y, mask, 64);
            cs[m].z += __shfl_xor(cs[m].z, mask, 64);
            cs[m].w += __shfl_xor(cs[m].w, mask, 64);
        }
    }
    if (kk == 0) {
#pragma unroll
        for (int m = 0; m < 8; ++m) {
            int nb = 32 * (m >> 1) + 8 * g + 4 * (m & 1);
            red[w * N_ + nb + 0] = cs[m].x;
            red[w * N_ + nb + 1] = cs[m].y;
            red[w * N_ + nb + 2] = cs[m].z;
            red[w * N_ + nb + 3] = cs[m].w;
        }
    }
    __syncthreads();
    if (tid < N_)
        part[blk * N_ + tid] = (red[tid] + red[N_ + tid])
                             + (red[2*N_ + tid] + red[3*N_ + tid]);
}

// K3: one block per (bh,spl), reverse dispatch order (L3-freshest first).
// Prologue: mean from part + gm. Hot loop: logit from own fp16 P row
// (16 fma), unshifted exp (|l|<=4), weighted accumulate.
__global__ __launch_bounds__(256, 4) void k_att(const float* __restrict__ hyp,
                                                const float* __restrict__ part,
                                                const float* __restrict__ Wmw,
                                                const float* __restrict__ Wmb,
                                                const float* __restrict__ Whw,
                                                const __half* __restrict__ Pbuf,
                                                float* __restrict__ attp) {
    __shared__ float red[4 * N_];
    __shared__ float zred[4];
    __shared__ float m_l[N_];
    __shared__ float gw_l[NK];
    const int tid  = threadIdx.x;
    const int lane = tid & 63;
    const int w    = tid >> 6;
    const int blk  = (B_ * H_ * TSPL - 1) - (int)blockIdx.x;
    const int bh   = blk >> 3;
    const int spl  = blk & 7;
    const int b = bh >> 3, h = bh & 7;
    const int t0 = spl * TBLK;
    const float4* hyp4 = (const float4*)hyp;
    const int base4 = b * (D_ / 4) + h * (N_ / 4);
    const int kk = lane & 15;
    const int g  = lane >> 4;

    // mean for this bh
    if (tid < N_) {
        float s = 0.f;
#pragma unroll
        for (int s8 = 0; s8 < TSPL; ++s8) s += part[(bh * TSPL + s8) * N_ + tid];
        m_l[tid] = s * (1.f / (float)T_);
    }
    __syncthreads();
    // gm: gw_l[k] = tanh(m.Wmw_k + Wmb_k) * Whw_k
    if (tid < N_) {
        int k = tid >> 3, g3 = tid & 7;
        float dsum = 0.f;
#pragma unroll
        for (int i = 0; i < 16; ++i) {
            int n = g3 * 16 + i;
            dsum = fmaf(m_l[n], Wmw[k * N_ + n], dsum);
        }
        dsum += __shfl_xor(dsum, 1, 64);
        dsum += __shfl_xor(dsum, 2, 64);
        dsum += __shfl_xor(dsum, 4, 64);
        if (g3 == 0) gw_l[k] = tanhf(dsum + Wmb[k]) * Whw[k];
    }
    __syncthreads();
    float gmv[NK];
#pragma unroll
    for (int j = 0; j < NK; ++j) gmv[j] = gw_l[j];

    float4 cacc[8];
#pragma unroll
    for (int m = 0; m < 8; ++m) cacc[m] = make_float4(0.f, 0.f, 0.f, 0.f);
    float zacc = 0.f;

#pragma unroll
    for (int step = 0; step < 4; ++step) {
        const int tr = t0 + step * 64 + w * 16 + kk;
        // own P row: 16 fp16 = 32 B = 2 uint4
        union { uint4 u; __half2 h[8]; } P0, P1;
        const uint4* pv = (const uint4*)(Pbuf + (size_t)(bh * T_ + tr) * NK);
        P0.u = pv[0]; P1.u = pv[1];
        float4 xq[8];
        LOADX(xq, step);
        float lg = 0.f;
#pragma unroll
        for (int q = 0; q < 4; ++q) {
            float2 f0 = __half22float2(P0.h[q]);
            float2 f1 = __half22float2(P1.h[q]);
            lg = fmaf(f0.x, gmv[2*q + 0], lg);
            lg = fmaf(f0.y, gmv[2*q + 1], lg);
            lg = fmaf(f1.x, gmv[8 + 2*q + 0], lg);
            lg = fmaf(f1.y, gmv[8 + 2*q + 1], lg);
        }
        float e = exp2f(lg * LOG2E);     // unshifted: |lg| <= sum|Whw| <= 4
        zacc += e;
#pragma unroll
        for (int m = 0; m < 8; ++m) {
            cacc[m].x = fmaf(e, xq[m].x, cacc[m].x);
            cacc[m].y = fmaf(e, xq[m].y, cacc[m].y);
            cacc[m].z = fmaf(e, xq[m].z, cacc[m].z);
            cacc[m].w = fmaf(e, xq[m].w, cacc[m].w);
        }
    }
    // reduce cacc and z over kk (lane bits 0-3)
#pragma unroll
    for (int m = 0; m < 8; ++m) {
#pragma unroll
        for (int mask = 1; mask <= 8; mask <<= 1) {
            cacc[m].x += __shfl_xor(cacc[m].x, mask, 64);
            cacc[m].y += __shfl_xor(cacc[m].y, mask, 64);
            cacc[m].z += __shfl_xor(cacc[m].z, mask, 64);
            cacc[m].w += __shfl_xor(cacc[m].w, mask, 64);
        }
    }
    float z = zacc;
    z += __shfl_xor(z, 1, 64);
    z += __shfl_xor(z, 2, 64);
    z += __shfl_xor(z, 4, 64);
    z += __shfl_xor(z, 8, 64);
    if (kk == 0) {
#pragma unroll
        for (int m = 0; m < 8; ++m) {
            int nb = 32 * (m >> 1) + 8 * g + 4 * (m & 1);
            red[w * N_ + nb + 0] = cacc[m].x;
            red[w * N_ + nb + 1] = cacc[m].y;
            red[w * N_ + nb + 2] = cacc[m].z;
            red[w * N_ + nb + 3] = cacc[m].w;
        }
    }
    if (lane == 0) zred[w] = z;
    __syncthreads();
    if (tid < N_) {
        attp[(size_t)blk * APS + tid] =
            (red[tid] + red[N_ + tid]) + (red[2*N_ + tid] + red[3*N_ + tid]);
    } else if (tid == N_) {
        attp[(size_t)blk * APS + N_] =
            (zred[0] + zred[1]) + (zred[2] + zred[3]);
    }
}

// K4: merge TSPL split partials per (b,h): c = sum ci / sum Zi
__global__ __launch_bounds__(128) void k_red(const float* __restrict__ attp,
                                             float* __restrict__ out) {
    int bh = blockIdx.x, tid = threadIdx.x;
    float Z = 0.f, c = 0.f;
#pragma unroll
    for (int s = 0; s < TSPL; ++s) {
        const float* pp = &attp[(size_t)(bh * TSPL + s) * APS];
        Z += pp[N_];
        c += pp[tid];
    }
    out[bh * N_ + tid] = c / Z;
}

extern "C" void kernel_launch(void* const* d_in, const int* in_sizes, int n_in,
                              void* d_out, int out_size, void* d_ws, size_t ws_size,
                              hipStream_t stream) {
    const float* hyp = (const float*)d_in[0];
    const float* Ww  = (const float*)d_in[1];
    const float* Wb  = (const float*)d_in[2];
    const float* Wmw = (const float*)d_in[3];
    const float* Wmb = (const float*)d_in[4];
    const float* Whw = (const float*)d_in[5];
    // d_in[6] = Wh_b: unused (softmax shift-invariant)
    float* out  = (float*)d_out;
    float* part = (float*)d_ws;                  // 2048*128 f  = 1 MB
    float* attp = part + 2048 * N_;              // 2048*132 f ~= 1.06 MB
    __half* Pbuf = (__half*)((char*)d_ws + (4 << 20));  // 16 MB fp16 P

    k_p  <<<dim3(B_ * H_ * TSPL), 256, 0, stream>>>(hyp, Ww, Wb, part, Pbuf);
    k_att<<<dim3(B_ * H_ * TSPL), 256, 0, stream>>>(hyp, part, Wmw, Wmb, Whw,
                                                    Pbuf, attp);
    k_red<<<dim3(B_ * H_), 128, 0, stream>>>(attp, out);
}